// Round 6
// baseline (61.844 us; speedup 1.0000x reference)
//
#include <hip/hip_runtime.h>
#include <hip/hip_bf16.h>

#define NCLS 13
#define HH 120
#define WW 160
#define HWSZ (HH * WW)       // 19200
#define PSAMP 1200           // 19200 / 16
#define CM1 (NCLS - 1)       // 12
#define NBLK 75              // HWSZ / 256
#define NVOTE (NBLK * CM1)   // 900 blocks total

// Squared-domain screen around T=0.9f (T^2 = 0.8099999571...), band covers
// sqrt+div+mul rounding (<=2.4e-7 rel each); ambiguous band -> exact ref path.
#define C_HI 0.8100011f
#define C_LO 0.8099988f

// ---------------- workspace layout (bytes) ----------------
// pcnt:  int  [12][75] @ 0      num_label partials   (slot-written, no init)
// pdz:   float[12][75] @ 3600   dz-sum partials      (slot-written, no init)
// bbest: int  [12][75] @ 7200   per-block argmax key (slot-written, no init)
// bns:   int  [12]     @ 10800  sampled count/class  (same value x75, no init)
// done:  uint [1]      @ 10848  modulo-900 counter   (ANY initial value works)

__global__ void __launch_bounds__(256) hough_all(
    const int* __restrict__ labels,
    const int* __restrict__ masks,
    const float* __restrict__ vp,
    const float* __restrict__ extents,
    const float* __restrict__ meta,
    int* __restrict__ pcnt,
    float* __restrict__ pdz,
    int* __restrict__ bbest,
    int* __restrict__ bns,
    unsigned int* __restrict__ done,
    float* __restrict__ out)
{
    const int bid = blockIdx.x;
    const int c1  = bid / NBLK;          // 0..11
    const int b   = bid - c1 * NBLK;     // 0..74
    const int c   = c1 + 1;
    const int tid = threadIdx.x;

    __shared__ float4 s[PSAMP];
    __shared__ int   s_n;
    __shared__ float s_dzw[4];
    __shared__ int   s_ctw[4];
    __shared__ int   wmax[4];
    __shared__ int   is_last;

    if (tid == 0) s_n = 0;
    __syncthreads();

    // Phase A: this block's 256-pixel slice stats for class c (fixed shfl tree)
    {
        const int i = b * 256 + tid;
        const int lab = labels[i];
        const bool m = (lab == c) && (masks[i] > 0);
        float dzv = m ? vp[(3 * c + 2) * HWSZ + i] : 0.f;
        unsigned long long bl = __ballot(m);
        for (int off = 32; off > 0; off >>= 1) dzv += __shfl_xor(dzv, off);
        if ((tid & 63) == 0) {
            s_ctw[tid >> 6] = (int)__popcll(bl);
            s_dzw[tid >> 6] = dzv;
        }
    }

    // Phase B: stage the full sampled pixel list of class c (order irrelevant:
    // votes are an order-independent sum; argmax key is an integer max)
    for (int p = tid; p < PSAMP; p += 256) {
        const int i = p << 4;
        if (labels[i] == c && masks[i] > 0) {
            float dx = vp[(3 * c + 0) * HWSZ + i];
            float dy = vp[(3 * c + 1) * HWSZ + i];
            float dn = __fadd_rn(
                __fsqrt_rn(__fadd_rn(__fmul_rn(dx, dx), __fmul_rn(dy, dy))),
                1e-6f);
            int k = atomicAdd(&s_n, 1);          // LDS atomic
            s[k] = make_float4((float)(i % WW), (float)(i / WW),
                               __fdiv_rn(dx, dn), __fdiv_rn(dy, dn));
        }
    }
    __syncthreads();
    const int n = s_n;

    // Phase C: vote for this block's 256 centers (bit-exact screened predicate)
    const int g = b * 256 + tid;
    const float xg = (float)(g % WW);
    const float yg = (float)(g / WW);
    int v = 0;
    for (int j = 0; j < n; ++j) {
        float4 e = s[j];
        float ddx = __fsub_rn(xg, e.x);          // exact (small ints)
        float ddy = __fsub_rn(yg, e.y);
        float d2  = __fadd_rn(__fmul_rn(ddx, ddx), __fmul_rn(ddy, ddy));
        float t2  = __fadd_rn(__fmul_rn(ddx, e.z), __fmul_rn(ddy, e.w));
        float q  = t2 * t2;
        float hi = C_HI * d2;
        float lo = C_LO * d2;
        bool in;
        if (q <= hi && q >= lo) {                // rare ambiguous band: exact path
            float dist = __fsqrt_rn(d2);
            float cosang = __fdiv_rn(t2, fmaxf(dist, 1e-6f));
            in = (cosang > 0.9f) && (dist > 0.0f);
        } else {
            in = (t2 > 0.0f) && (q > hi);
        }
        v += in ? 1 : 0;
    }

    // Phase D: block argmax. key = (v<<15)|(19199-g): max v wins, tie -> min g.
    int key = (v << 15) | (19199 - g);
    for (int off = 32; off > 0; off >>= 1) {
        int o = __shfl_xor(key, off);
        key = key > o ? key : o;
    }
    if ((tid & 63) == 0) wmax[tid >> 6] = key;
    __syncthreads();

    // Phase E: slot writes + done counter; exactly one block finalizes.
    if (tid == 0) {
        int k01 = wmax[0] > wmax[1] ? wmax[0] : wmax[1];
        int k23 = wmax[2] > wmax[3] ? wmax[2] : wmax[3];
        bbest[bid] = k01 > k23 ? k01 : k23;
        pcnt[bid]  = s_ctw[0] + s_ctw[1] + s_ctw[2] + s_ctw[3];
        pdz[bid]   = ((s_dzw[0] + s_dzw[1]) + s_dzw[2]) + s_dzw[3];
        bns[c1]    = n;                          // same value from all 75 blocks
        __threadfence();                         // publish slots (device scope)
        unsigned int old = atomicAdd(done, 1u);  // works from ANY initial value
        is_last = ((old % (unsigned)NVOTE) == (unsigned)(NVOTE - 1)) ? 1 : 0;
    }
    __syncthreads();
    if (!is_last) return;
    __threadfence();                             // acquire published slots

    // ---------------- finalize (exactly one block) ----------------
    float* top_box    = out;          // 12 x 7
    float* top_pose   = out + 84;     // 12 x 7
    float* top_target = out + 168;    // 12 x 52
    float* top_weight = out + 792;    // 12 x 52
    float* top_domain = out + 1416;   // 12

    for (int j = tid; j < 624; j += 256) top_target[j] = 0.f;
    if (tid >= 244) top_domain[tid - 244] = 0.f;

    __shared__ int   r_nl[CM1][16];
    __shared__ float r_dz[CM1][16];
    __shared__ int   r_bk[CM1][16];
    if (tid < CM1 * 16) {
        const int cc = tid >> 4, l = tid & 15;
        int nl = 0; float ds = 0.f; int bk = 0;  // min possible key is 0
        for (int bb = l; bb < NBLK; bb += 16) {
            nl += pcnt[cc * NBLK + bb];
            ds += pdz [cc * NBLK + bb];
            int kk = bbest[cc * NBLK + bb];
            bk = kk > bk ? kk : bk;
        }
        r_nl[cc][l] = nl; r_dz[cc][l] = ds; r_bk[cc][l] = bk;
    }
    __syncthreads();
    for (int st = 8; st > 0; st >>= 1) {
        if (tid < CM1 * 16) {
            const int cc = tid >> 4, l = tid & 15;
            if (l < st) {
                r_nl[cc][l] += r_nl[cc][l + st];
                r_dz[cc][l] += r_dz[cc][l + st];
                int kk = r_bk[cc][l + st];
                if (kk > r_bk[cc][l]) r_bk[cc][l] = kk;
            }
        }
        __syncthreads();
    }

    if (tid < CM1) {
        const int cc = tid, c2 = tid + 1;
        const int nl = r_nl[cc][0];
        const int ns = bns[cc];
        const float ds = r_dz[cc][0];
        const int key2 = r_bk[cc][0];
        const float vmax = (float)(key2 >> 15);
        const int bi = 19199 - (key2 & 32767);
        const float cx = (float)(bi % WW);
        const float cy = (float)(bi / WW);
        const float msum = fmaxf((float)nl, 1.0f);
        float z = expf(ds / msum);
        z = fmaxf(z, 1e-3f);
        const float fx = meta[0], fy = meta[4], pxc = meta[2], pyc = meta[5];
        const float bw = extents[c2 * 3 + 0] * fx / z;
        const float bh = extents[c2 * 3 + 1] * fy / z;
        const float nsamp = fmaxf((float)ns, 1.0f);
        const bool valid = (vmax >= 10.0f) && (nl >= 500) &&
                           (vmax >= 0.02f * nsamp);

        float* bx = top_box + cc * 7;
        bx[0] = 0.0f;
        bx[1] = (float)c2;
        bx[2] = cx - bw * 0.5f;
        bx[3] = cy - bh * 0.5f;
        bx[4] = cx + bw * 0.5f;
        bx[5] = cy + bh * 0.5f;
        bx[6] = vmax;

        const float tx = (cx - pxc) * z / fx;
        const float ty = (cy - pyc) * z / fy;
        float* ps = top_pose + cc * 7;
        ps[0] = 1.f; ps[1] = 0.f; ps[2] = 0.f; ps[3] = 0.f;
        ps[4] = tx;  ps[5] = ty;  ps[6] = z;

        float* wt = top_weight + cc * 52;
        const float wv = valid ? 1.0f : 0.0f;
        for (int j = 0; j < 52; ++j)
            wt[j] = ((j >> 2) == c2) ? wv : 0.0f;
    }
}

extern "C" void kernel_launch(void* const* d_in, const int* in_sizes, int n_in,
                              void* d_out, int out_size, void* d_ws, size_t ws_size,
                              hipStream_t stream) {
    const int*   labels  = (const int*)d_in[0];
    const int*   masks   = (const int*)d_in[1];
    const float* vp      = (const float*)d_in[2];
    const float* extents = (const float*)d_in[3];
    const float* meta    = (const float*)d_in[5];
    float* out = (float*)d_out;

    char* ws = (char*)d_ws;
    int*          pcnt  = (int*)          (ws + 0);
    float*        pdz   = (float*)        (ws + 3600);
    int*          bbest = (int*)          (ws + 7200);
    int*          bns   = (int*)          (ws + 10800);
    unsigned int* done  = (unsigned int*) (ws + 10848);

    hough_all<<<dim3(NVOTE), dim3(256), 0, stream>>>(
        labels, masks, vp, extents, meta, pcnt, pdz, bbest, bns, done, out);
}

// Round 7
// 37.256 us; speedup vs baseline: 1.6600x; 1.6600x over previous
//
#include <hip/hip_runtime.h>
#include <hip/hip_bf16.h>

#define NCLS 13
#define HH 120
#define WW 160
#define HWSZ (HH * WW)       // 19200
#define PSAMP 1200           // 19200 / 16
#define CM1 (NCLS - 1)       // 12
#define NBLK 75              // HWSZ / 256

// ---------------- workspace layout (bytes) ----------------
// praw:  float4[12][75][16] @ 0        (230400 B)  ragged per-block lists
// bcnt:  int   [12][75]     @ 230400   (3600 B)    per-block sampled counts
// pcnt:  int   [12][75]     @ 234000   (3600 B)    per-block num_label partials
// pdz:   float [12][75]     @ 237600   (3600 B)    per-block dz-sum partials
// best:  int   [12]         @ 241200   (48 B)      packed argmax keys
// total 241248 B — no pre-initialization required (best zeroed in prep).

// Kernel 1: one thread per pixel. Per-block ragged compaction (LDS atomics
// only) + per-block per-class (count, dz-sum) partials via shfl trees.
__global__ void hough_prep(const int* __restrict__ labels,
                           const int* __restrict__ masks,
                           const float* __restrict__ vp,
                           float4* __restrict__ praw,
                           int* __restrict__ bcnt,
                           int* __restrict__ pcnt,
                           float* __restrict__ pdz,
                           int* __restrict__ best) {
    const int tid = threadIdx.x;
    const int b = blockIdx.x;
    const int i = b * 256 + tid;                   // < 19200 exactly
    __shared__ int lcnt[CM1];
    if (tid < CM1) lcnt[tid] = 0;
    if (b == 0 && tid >= 64 && tid < 64 + CM1) best[tid - 64] = 0;  // vote runs later
    __syncthreads();

    const int lab = labels[i];
    const bool valid = (lab > 0) && (masks[i] > 0);
    const int cls = valid ? lab - 1 : -1;
    float dz = 0.f;
    if (valid) dz = vp[(3 * lab + 2) * HWSZ + i];

    // sampled compaction into this block's ragged slots (order irrelevant)
    if (valid && ((tid & 15) == 0)) {
        float dx = vp[(3 * lab + 0) * HWSZ + i];
        float dy = vp[(3 * lab + 1) * HWSZ + i];
        float dn = __fadd_rn(
            __fsqrt_rn(__fadd_rn(__fmul_rn(dx, dx), __fmul_rn(dy, dy))), 1e-6f);
        int k = atomicAdd(&lcnt[cls], 1);          // LDS atomic, <16/block
        praw[(cls * NBLK + b) * 16 + k] =
            make_float4((float)(i % WW), (float)(i / WW),
                        __fdiv_rn(dx, dn), __fdiv_rn(dy, dn));
    }

    // per-wave per-class reductions (fixed shuffle tree -> deterministic)
    __shared__ float s_dz[4][CM1];
    __shared__ int   s_ct[4][CM1];
    const int w = tid >> 6, lane = tid & 63;
    for (int c1 = 0; c1 < CM1; ++c1) {
        unsigned long long bl = __ballot(cls == c1);
        float v = (cls == c1) ? dz : 0.f;
        for (int off = 32; off > 0; off >>= 1) v += __shfl_xor(v, off);
        if (lane == 0) { s_ct[w][c1] = (int)__popcll(bl); s_dz[w][c1] = v; }
    }
    __syncthreads();
    if (tid < CM1) {
        bcnt[tid * NBLK + b] = lcnt[tid];
        pcnt[tid * NBLK + b] = s_ct[0][tid] + s_ct[1][tid] + s_ct[2][tid] + s_ct[3][tid];
        pdz [tid * NBLK + b] = ((s_dz[0][tid] + s_dz[1][tid]) + s_dz[2][tid]) + s_dz[3][tid];
    }
}

// Kernel 2: densify ragged lists in LDS, vote, fused argmax via atomicMax.
// key = (v << 15) | (19199 - g): max v wins, ties -> smallest g.
__global__ void hough_vote(const float4* __restrict__ praw,
                           const int* __restrict__ bcnt,
                           int* __restrict__ best) {
    const int c1 = blockIdx.y;                       // 0..11
    const int g  = blockIdx.x * 256 + threadIdx.x;   // 0..19199
    __shared__ float4 s[PSAMP];
    __shared__ int scnt[NBLK];
    __shared__ int soff[NBLK + 1];
    if (threadIdx.x < NBLK) scnt[threadIdx.x] = bcnt[c1 * NBLK + threadIdx.x];
    __syncthreads();
    if (threadIdx.x == 0) {
        int acc = 0;
        for (int b2 = 0; b2 < NBLK; ++b2) { soff[b2] = acc; acc += scnt[b2]; }
        soff[NBLK] = acc;
    }
    __syncthreads();
    for (int t = threadIdx.x; t < NBLK * 16; t += 256) {
        const int b2 = t >> 4, k = t & 15;
        if (k < scnt[b2]) s[soff[b2] + k] = praw[(c1 * NBLK + b2) * 16 + k];
    }
    const int n = soff[NBLK];
    __syncthreads();

    const float xg = (float)(g % WW);
    const float yg = (float)(g / WW);
    int v = 0;
    for (int j = 0; j < n; ++j) {
        float4 e = s[j];
        float ddx = __fsub_rn(xg, e.x);
        float ddy = __fsub_rn(yg, e.y);
        float d2  = __fadd_rn(__fmul_rn(ddx, ddx), __fmul_rn(ddy, ddy));
        float dist = __fsqrt_rn(d2);
        float t2 = __fadd_rn(__fmul_rn(ddx, e.z), __fmul_rn(ddy, e.w));
        float cosang = __fdiv_rn(t2, fmaxf(dist, 1e-6f));
        v += (cosang > 0.9f && dist > 0.0f) ? 1 : 0;
    }

    int key = (v << 15) | (19199 - g);
    for (int off = 32; off > 0; off >>= 1) {
        int o = __shfl_xor(key, off);
        key = key > o ? key : o;
    }
    __shared__ int wmax[4];
    if ((threadIdx.x & 63) == 0) wmax[threadIdx.x >> 6] = key;
    __syncthreads();
    if (threadIdx.x == 0) {
        int k01 = wmax[0] > wmax[1] ? wmax[0] : wmax[1];
        int k23 = wmax[2] > wmax[3] ? wmax[2] : wmax[3];
        atomicMax(&best[c1], k01 > k23 ? k01 : k23);
    }
}

// Kernel 3: single block — reduce partials, decode best keys, emit outputs.
__global__ void hough_out(const int* __restrict__ best,
                          const int* __restrict__ bcnt,
                          const int* __restrict__ pcnt,
                          const float* __restrict__ pdz,
                          const float* __restrict__ extents,
                          const float* __restrict__ meta,
                          float* __restrict__ out) {
    const int tid = threadIdx.x;
    float* top_box    = out;          // 12 x 7
    float* top_pose   = out + 84;     // 12 x 7
    float* top_target = out + 168;    // 12 x 52
    float* top_weight = out + 792;    // 12 x 52
    float* top_domain = out + 1416;   // 12

    for (int j = tid; j < 624; j += 256) top_target[j] = 0.f;
    if (tid >= 244) top_domain[tid - 244] = 0.f;

    if (tid < CM1) {
        const int c1 = tid, c = tid + 1;
        int nl = 0, ns = 0; float ds = 0.f;
        #pragma unroll
        for (int b = 0; b < NBLK; ++b) {
            nl += pcnt[c1 * NBLK + b];
            ns += bcnt[c1 * NBLK + b];
            ds += pdz [c1 * NBLK + b];
        }
        const int key = best[c1];
        const float vmax = (float)(key >> 15);
        const int bi = 19199 - (key & 32767);
        const float cx = (float)(bi % WW);
        const float cy = (float)(bi / WW);
        const float msum = fmaxf((float)nl, 1.0f);
        float z = expf(ds / msum);
        z = fmaxf(z, 1e-3f);
        const float fx = meta[0], fy = meta[4], pxc = meta[2], pyc = meta[5];
        const float bw = extents[c * 3 + 0] * fx / z;
        const float bh = extents[c * 3 + 1] * fy / z;
        const float nsamp = fmaxf((float)ns, 1.0f);
        const bool valid = (vmax >= 10.0f) && (nl >= 500) &&
                           (vmax >= 0.02f * nsamp);

        float* bx = top_box + c1 * 7;
        bx[0] = 0.0f;
        bx[1] = (float)c;
        bx[2] = cx - bw * 0.5f;
        bx[3] = cy - bh * 0.5f;
        bx[4] = cx + bw * 0.5f;
        bx[5] = cy + bh * 0.5f;
        bx[6] = vmax;

        const float tx = (cx - pxc) * z / fx;
        const float ty = (cy - pyc) * z / fy;
        float* ps = top_pose + c1 * 7;
        ps[0] = 1.f; ps[1] = 0.f; ps[2] = 0.f; ps[3] = 0.f;
        ps[4] = tx;  ps[5] = ty;  ps[6] = z;

        float* wt = top_weight + c1 * 52;
        const float wv = valid ? 1.0f : 0.0f;
        for (int j = 0; j < 52; ++j)
            wt[j] = ((j >> 2) == c) ? wv : 0.0f;
    }
}

extern "C" void kernel_launch(void* const* d_in, const int* in_sizes, int n_in,
                              void* d_out, int out_size, void* d_ws, size_t ws_size,
                              hipStream_t stream) {
    const int*   labels  = (const int*)d_in[0];
    const int*   masks   = (const int*)d_in[1];
    const float* vp      = (const float*)d_in[2];
    const float* extents = (const float*)d_in[3];
    const float* meta    = (const float*)d_in[5];
    float* out = (float*)d_out;

    char* ws = (char*)d_ws;
    float4* praw = (float4*)(ws + 0);
    int*    bcnt = (int*)   (ws + 230400);
    int*    pcnt = (int*)   (ws + 234000);
    float*  pdz  = (float*) (ws + 237600);
    int*    best = (int*)   (ws + 241200);

    hough_prep<<<dim3(NBLK), dim3(256), 0, stream>>>(labels, masks, vp,
                                                     praw, bcnt, pcnt, pdz, best);
    hough_vote<<<dim3(NBLK, CM1), dim3(256), 0, stream>>>(praw, bcnt, best);
    hough_out<<<dim3(1), dim3(256), 0, stream>>>(best, bcnt, pcnt, pdz,
                                                 extents, meta, out);
}